// Round 12
// baseline (552.361 us; speedup 1.0000x reference)
//
#include <hip/hip_runtime.h>

constexpr int NN   = 50000;   // nodes
constexpr int NPAD = 50016;   // padded (divisible by 16) for layer tiles
constexpr int NE   = 600000;  // edges
constexpr int NG   = 512;     // graphs
constexpr int HD   = 128;     // hidden
constexpr float BN_EPS = 1e-5f;
constexpr int CWS  = HD*HD + 2*HD + HD;  // per-layer f32 slot: Wc[128x128], wce[2x128], bc[128]
constexpr int WMF_L = 2*4*4*128*8;       // per-layer split-weight table (ushorts): [hi|lo][ks][ksub][col][8]
constexpr int TR   = 16;                 // rows per k_layer tile
constexpr int DEG_BLOCKS = (NE + 255) / 256;   // 2344
constexpr int CMB_UNITS  = 8 * 131;            // (layer, row) units for combine
constexpr int CMB_BLOCKS = CMB_UNITS / 2;      // 524 blocks x 2 units (128 thr each)

typedef __attribute__((ext_vector_type(8))) short bf16x8;
typedef __attribute__((ext_vector_type(4))) float f32x4;

__device__ inline unsigned short bf16rne(float v) {
  unsigned u = __float_as_uint(v);
  return (unsigned short)((u + 0x7FFFu + ((u >> 16) & 1u)) >> 16);
}
// split f32 into hi+lo bf16 (v ~= hi + lo, error ~2^-18 relative)
__device__ inline void bfsplit(float v, unsigned short& h, unsigned short& l) {
  unsigned short hb = bf16rne(v);
  float hf = __uint_as_float((unsigned)hb << 16);
  l = bf16rne(v - hf);
  h = hb;
}
__device__ inline float blo(unsigned u) { return __uint_as_float(u << 16); }
__device__ inline float bhi(unsigned u) { return __uint_as_float(u & 0xFFFF0000u); }

// ---------------- fused deg histogram + combined-weight build (independent work) ----------------

__global__ __launch_bounds__(256) void k_deg_combine(
    const int* __restrict__ ei, int* __restrict__ deg, int* __restrict__ rank,
    const float* __restrict__ We0, const float* __restrict__ be0, const float* __restrict__ Wn0,
    const float* __restrict__ We_s, const float* __restrict__ be_s, const float* __restrict__ Wn_s,
    float* __restrict__ cw, unsigned short* __restrict__ wmf) {
  int b = blockIdx.x;
  if (b < DEG_BLOCKS) {
    int e = b * 256 + threadIdx.x;
    if (e < NE) rank[e] = atomicAdd(&deg[ei[NE + e]], 1);
    return;
  }
  int u = (b - DEG_BLOCKS) * 2 + (threadIdx.x >> 7);
  int l = u / 131, r = u % 131, j = threadIdx.x & 127;
  float* slot = cw + (size_t)l * CWS;
  const float* Wn;
  const float* Arow;
  float* dst;
  if (l == 0) {
    Wn = Wn0;
    if (r < 4)       { Arow = We0 + r * HD; dst = slot + r * HD; }
    else if (r < 6)  { Arow = We0 + r * HD; dst = slot + HD * HD + (r - 4) * HD; }
    else if (r == 6) { Arow = be0;          dst = slot + HD * HD + 2 * HD; }
    else return;
  } else {
    int li = l - 1;
    Wn = Wn_s + (size_t)li * HD * HD;
    const float* We = We_s + (size_t)li * 130 * HD;
    if (r < 128)      { Arow = We + r * HD;  dst = slot + r * HD; }
    else if (r < 130) { Arow = We + r * HD;  dst = slot + HD * HD + (r - 128) * HD; }
    else              { Arow = be_s + li * HD; dst = slot + HD * HD + 2 * HD; }
  }
  float acc = 0.f;
  for (int t = 0; t < HD; t++) acc = fmaf(Arow[t], Wn[t * HD + j], acc);
  dst[j] = acc;
  if (l >= 1 && r < 128) {
    unsigned short hb, lb;
    bfsplit(acc, hb, lb);
    size_t wbase = (size_t)(l - 1) * WMF_L;
    int kb = r >> 5, ks2 = (r >> 3) & 3, jj = r & 7;  // k = r
    size_t o = (size_t)((kb * 4 + ks2) * 128 + j) * 8 + jj;
    wmf[wbase + o] = hb;
    wmf[wbase + WMF_L / 2 + o] = lb;
  }
}

// ---------------- scans ----------------

__global__ __launch_bounds__(1024) void k_scanA(const int* __restrict__ deg,
                                                int* __restrict__ rowptr, int* __restrict__ bsum) {
  __shared__ int sm[1024];
  int t = threadIdx.x, b = blockIdx.x;
  int i = b * 1024 + t;
  int v = (i < NN) ? deg[i] : 0;
  sm[t] = v;
  __syncthreads();
  for (int off = 1; off < 1024; off <<= 1) {
    int add = (t >= off) ? sm[t - off] : 0;
    __syncthreads();
    sm[t] += add;
    __syncthreads();
  }
  int incl = sm[t];
  if (i < NN) rowptr[i] = incl - v;   // exclusive within chunk
  if (t == 1023) bsum[b] = incl;
}

// scanB folded in: each block serially prefixes the 49 chunk sums itself
__global__ __launch_bounds__(1024) void k_scanC(int* rowptr, const int* __restrict__ bsum) {
  __shared__ int base;
  int b = blockIdx.x;
  if (threadIdx.x == 0) {
    int acc = 0;
    for (int j = 0; j < b; j++) acc += bsum[j];
    base = acc;
    if (b == 0) rowptr[NN] = NE;
  }
  __syncthreads();
  int i = b * 1024 + threadIdx.x;
  if (i < NN) rowptr[i] += base;
}

// atomic-free scatter of src index + permuted edge_attr into CSR order
__global__ __launch_bounds__(256) void k_scatter(
    const int* __restrict__ ei, const float* __restrict__ ea, const int* __restrict__ rowptr,
    const int* __restrict__ rank, int* __restrict__ csr, float* __restrict__ eap) {
  int e = blockIdx.x * 256 + threadIdx.x;
  if (e >= NE) return;
  int s = ei[e], d = ei[NE + e];
  int pos = rowptr[d] + rank[e];
  csr[pos] = s;
  *(float2*)(eap + 2 * (size_t)pos) = *(const float2*)(ea + 2 * (size_t)e);
}

// ---------------- fused node_pre + layer0: per-node sums -> K=4 conv -> hi/lo planes ----------------
// 32-lane group per node; xor-reduce leaves sums in ALL lanes; each lane computes 4 channels.
__global__ __launch_bounds__(256) void k_node0(
    const int* __restrict__ rowptr, const int* __restrict__ csr, const float* __restrict__ eap,
    const float* __restrict__ x, const int* __restrict__ deg, const float* __restrict__ cw0,
    const float* __restrict__ bno0, const float* __restrict__ g0, const float* __restrict__ bt0,
    const float* __restrict__ m0, const float* __restrict__ v0,
    const float* __restrict__ Wr0, const float* __restrict__ br0,
    float* __restrict__ Se, unsigned short* __restrict__ outHi, unsigned short* __restrict__ outLo) {
  int g32 = threadIdx.x >> 5;
  int i = blockIdx.x * 8 + g32;
  if (i >= NN) return;
  int l = threadIdx.x & 31;
  int e0 = rowptr[i], e1 = rowptr[i + 1];
  float sx0 = 0.f, sx1 = 0.f, sx2 = 0.f, sx3 = 0.f, se0 = 0.f, se1 = 0.f;
  for (int e = e0 + l; e < e1; e += 32) {
    int s = csr[e];
    float4 xv = *(const float4*)(x + 4 * (size_t)s);
    sx0 += xv.x; sx1 += xv.y; sx2 += xv.z; sx3 += xv.w;
    float2 ev = *(const float2*)(eap + 2 * (size_t)e);
    se0 += ev.x; se1 += ev.y;
  }
#pragma unroll
  for (int m = 1; m <= 16; m <<= 1) {
    sx0 += __shfl_xor(sx0, m); sx1 += __shfl_xor(sx1, m);
    sx2 += __shfl_xor(sx2, m); sx3 += __shfl_xor(sx3, m);
    se0 += __shfl_xor(se0, m); se1 += __shfl_xor(se1, m);
  }
  if (l == 0) *(float2*)(Se + 2 * (size_t)i) = make_float2(se0, se1);
  // layer0 compute for channels c = l*4 .. l*4+3
  float dg = (float)deg[i];
  float dgi = 1.0f / fmaxf(dg, 1.0f);
  float4 xr = *(const float4*)(x + 4 * (size_t)i);
  const float* Wc0  = cw0;                 // [4][128]
  const float* wce0 = cw0 + HD * HD;       // [2][128]
  const float* bc0  = cw0 + HD * HD + 2 * HD;
  ushort4 hs, ls;
  unsigned short* hp = (unsigned short*)&hs;
  unsigned short* lp = (unsigned short*)&ls;
#pragma unroll
  for (int k2 = 0; k2 < 4; k2++) {
    int c = l * 4 + k2;
    float y = sx0 * Wc0[c] + sx1 * Wc0[HD + c] + sx2 * Wc0[2 * HD + c] + sx3 * Wc0[3 * HD + c];
    y += se0 * wce0[c] + se1 * wce0[HD + c] + dg * bc0[c];
    y = y * dgi + bno0[c];
    float sc = g0[c] * rsqrtf(v0[c] + BN_EPS);
    y = (y - m0[c]) * sc + bt0[c];
    float r = br0[c] + xr.x * Wr0[c] + xr.y * Wr0[HD + c] + xr.z * Wr0[2 * HD + c] + xr.w * Wr0[3 * HD + c];
    float o = fmaxf(y + r, 0.f);
    bfsplit(o, hp[k2], lp[k2]);
  }
  *(ushort4*)(outHi + (size_t)i * HD + l * 4) = hs;
  *(ushort4*)(outLo + (size_t)i * HD + l * 4) = ls;
}

// ---------------- fused layer: half-per-row gather + MFMA GEMM + epilogue ----------------
// R10 form (best measured): each 32-lane half owns one row (uint2/lane = one load
// instruction covers 2 edges / 512 B / 8 lines), 4-deep unroll, register
// accumulators, no shfl, no atomics. MLP beyond 4/half measured as saturated
// (R7 joint-8 == R9 serial-4 == 48 us @TR=32; R11 quarter-wave regressed).

__global__ __launch_bounds__(256, 8) void k_layer(
    const unsigned short* __restrict__ hHi, const unsigned short* __restrict__ hLo,
    const int* __restrict__ rowptr, const int* __restrict__ csr,
    const float* __restrict__ cwl, const unsigned short* __restrict__ wmf,
    const float* __restrict__ bno, const float* __restrict__ gam, const float* __restrict__ bet,
    const float* __restrict__ mu, const float* __restrict__ var,
    const float* __restrict__ Se, const int* __restrict__ deg,
    unsigned short* __restrict__ outHi, unsigned short* __restrict__ outLo) {
  __shared__ unsigned short St_hi[TR * 136];  // 136-pad, 16B-aligned rows
  __shared__ unsigned short St_lo[TR * 136];
  int tid = threadIdx.x;
  int wid = tid >> 6, lane = tid & 63;
  int half = lane >> 5, l5 = lane & 31;
  int rowbase = blockIdx.x * TR;
  const uint2* hb2 = (const uint2*)hHi;   // bf16 row = 32 uint2 = 256 B

  // ---- phase A: each half aggregates 2 rows (its parity of the wave's 4) ----
#pragma unroll
  for (int rp = 0; rp < 2; rp++) {
    int lr = wid * 4 + rp * 2 + half;
    int i = rowbase + lr;
    int e = 0, e1 = 0;
    if (i < NN) { e = rowptr[i]; e1 = rowptr[i + 1]; }
    float a0 = 0.f, a1 = 0.f, a2 = 0.f, a3 = 0.f;
    for (; e + 3 < e1; e += 4) {          // 4 loads in flight per half
      int s0 = csr[e], s1 = csr[e + 1], s2 = csr[e + 2], s3 = csr[e + 3];
      uint2 v0 = hb2[(size_t)s0 * 32 + l5];
      uint2 v1 = hb2[(size_t)s1 * 32 + l5];
      uint2 v2 = hb2[(size_t)s2 * 32 + l5];
      uint2 v3 = hb2[(size_t)s3 * 32 + l5];
      a0 += blo(v0.x) + blo(v1.x) + blo(v2.x) + blo(v3.x);
      a1 += bhi(v0.x) + bhi(v1.x) + bhi(v2.x) + bhi(v3.x);
      a2 += blo(v0.y) + blo(v1.y) + blo(v2.y) + blo(v3.y);
      a3 += bhi(v0.y) + bhi(v1.y) + bhi(v2.y) + bhi(v3.y);
    }
    if (e + 1 < e1) {
      int s0 = csr[e], s1 = csr[e + 1];
      uint2 v0 = hb2[(size_t)s0 * 32 + l5];
      uint2 v1 = hb2[(size_t)s1 * 32 + l5];
      a0 += blo(v0.x) + blo(v1.x); a1 += bhi(v0.x) + bhi(v1.x);
      a2 += blo(v0.y) + blo(v1.y); a3 += bhi(v0.y) + bhi(v1.y);
      e += 2;
    }
    if (e < e1) {
      uint2 v = hb2[(size_t)csr[e] * 32 + l5];
      a0 += blo(v.x); a1 += bhi(v.x); a2 += blo(v.y); a3 += bhi(v.y);
    }
    unsigned short h0, l0, h1, l1, h2, l2, h3, l3;
    bfsplit(a0, h0, l0); bfsplit(a1, h1, l1); bfsplit(a2, h2, l2); bfsplit(a3, h3, l3);
    *(ushort4*)&St_hi[lr * 136 + l5 * 4] = make_ushort4(h0, h1, h2, h3);
    *(ushort4*)&St_lo[lr * 136 + l5 * 4] = make_ushort4(l0, l1, l2, l3);
  }
  __syncthreads();

  // ---- phase B: MFMA GEMM. Wave grid 1(M)x4(N): 16 rows x 32 cols per wave ----
  int nlane = lane & 15, ksub = lane >> 4;
  const unsigned short* wh = wmf;                 // hi table [ks][ksub][col][8]
  const unsigned short* wl = wmf + WMF_L / 2;     // lo table
  f32x4 acc[2];
#pragma unroll
  for (int nt = 0; nt < 2; nt++) acc[nt] = (f32x4){0.f, 0.f, 0.f, 0.f};
#pragma unroll
  for (int ks = 0; ks < 4; ks++) {
    bf16x8 ah = *(const bf16x8*)&St_hi[nlane * 136 + ks * 32 + ksub * 8];
    bf16x8 al = *(const bf16x8*)&St_lo[nlane * 136 + ks * 32 + ksub * 8];
#pragma unroll
    for (int nt = 0; nt < 2; nt++) {
      int col = wid * 32 + nt * 16 + nlane;
      bf16x8 bh = *(const bf16x8*)&wh[(size_t)((ks * 4 + ksub) * 128 + col) * 8];
      bf16x8 bl = *(const bf16x8*)&wl[(size_t)((ks * 4 + ksub) * 128 + col) * 8];
      acc[nt] = __builtin_amdgcn_mfma_f32_16x16x32_bf16(ah, bh, acc[nt], 0, 0, 0);
      acc[nt] = __builtin_amdgcn_mfma_f32_16x16x32_bf16(al, bh, acc[nt], 0, 0, 0);
      acc[nt] = __builtin_amdgcn_mfma_f32_16x16x32_bf16(ah, bl, acc[nt], 0, 0, 0);
    }
  }

  // ---- epilogue: C/D frag lane l reg i -> row=(l>>4)*4+i, col=(l&15)+16*nt ----
  const float* wce = cwl + HD * HD;
  const float* bcp = cwl + HD * HD + 2 * HD;
  int rb = ksub * 4;
  float dgv[4], dgiv[4];
  float2 sevv[4];
#pragma unroll
  for (int i2 = 0; i2 < 4; i2++) {
    size_t row = (size_t)rowbase + rb + i2;
    float dg = (float)deg[row];
    dgv[i2] = dg;
    dgiv[i2] = 1.0f / fmaxf(dg, 1.0f);
    sevv[i2] = *(const float2*)(Se + row * 2);
  }
#pragma unroll
  for (int nt = 0; nt < 2; nt++) {
    int col = wid * 32 + nt * 16 + nlane;
    float w0 = wce[col], w1 = wce[HD + col], bcv = bcp[col], bnov = bno[col];
    float sc = gam[col] * rsqrtf(var[col] + BN_EPS);
    float sh = bet[col] - mu[col] * sc;
#pragma unroll
    for (int i2 = 0; i2 < 4; i2++) {
      size_t row = (size_t)rowbase + rb + i2;
      size_t idx = row * HD + col;
      float res = __uint_as_float((unsigned)hHi[idx] << 16)
                + __uint_as_float((unsigned)hLo[idx] << 16);
      float y = (acc[nt][i2] + sevv[i2].x * w0 + sevv[i2].y * w1 + dgv[i2] * bcv) * dgiv[i2] + bnov;
      y = fmaxf(y * sc + sh + res, 0.f);
      unsigned short yh, yl;
      bfsplit(y, yh, yl);
      outHi[idx] = yh;
      if (outLo) outLo[idx] = yl;   // last layer: pool reads Hi only -> skip Lo write
    }
  }
}

// ---------------- fused pooling + head: pooled vectors stay in LDS ----------------

__global__ __launch_bounds__(512) void k_poolhead(
    const unsigned short* __restrict__ hb, const int* __restrict__ batch,
    const float* __restrict__ W1, const float* __restrict__ b1,
    const float* __restrict__ g1, const float* __restrict__ bt1,
    const float* __restrict__ m1, const float* __restrict__ v1,
    const float* __restrict__ W2, const float* __restrict__ b2,
    float* __restrict__ outp) {
  __shared__ float ssum[512], smax[512];
  __shared__ float pmean[128], pmax[128];
  __shared__ float s1[128];
  __shared__ float red[512];
  int g = blockIdx.x, t = threadIdx.x;
  int d = t & 127, sub = t >> 7;   // 4-way row split
  int lo = 0, hi = NN;
  while (lo < hi) { int mid = (lo + hi) >> 1; if (batch[mid] < g) lo = mid + 1; else hi = mid; }
  int start = lo;
  lo = start; hi = NN;
  while (lo < hi) { int mid = (lo + hi) >> 1; if (batch[mid] < g + 1) lo = mid + 1; else hi = mid; }
  int end = lo;
  float sum = 0.f, mx = -3.4e38f;
  for (int i = start + sub; i < end; i += 4) {
    float val = __uint_as_float((unsigned)hb[(size_t)i * HD + d] << 16);
    sum += val;
    mx = fmaxf(mx, val);
  }
  ssum[t] = sum; smax[t] = mx;
  __syncthreads();
  if (sub == 0) {
    sum = ssum[t] + ssum[t + 128] + ssum[t + 256] + ssum[t + 384];
    mx = fmaxf(fmaxf(smax[t], smax[t + 128]), fmaxf(smax[t + 256], smax[t + 384]));
    int cnt = end - start;
    pmean[d] = sum / fmaxf((float)cnt, 1.f);
    pmax[d] = (cnt > 0) ? mx : 0.f;
  }
  __syncthreads();
  if (t < 128) {
    float y = b1[t];
    for (int k = 0; k < 128; k++) y = fmaf(pmean[k], W1[k * HD + t], y);
    for (int k = 0; k < 128; k++) y = fmaf(pmax[k], W1[(128 + k) * HD + t], y);
    float sc = g1[t] * rsqrtf(v1[t] + BN_EPS);
    y = (y - m1[t]) * sc + bt1[t];
    s1[t] = fmaxf(y, 0.f);
  }
  __syncthreads();
  float o = 0.f;
  if (t < 256) {
    o = b2[t];
    for (int k = 0; k < 128; k++) o = fmaf(s1[k], W2[k * 256 + t], o);
  }
  red[t] = o * o;
  __syncthreads();
  for (int off = 256; off > 0; off >>= 1) {
    if (t < off) red[t] += red[t + off];
    __syncthreads();
  }
  float scale = 1.0f / fmaxf(sqrtf(red[0]), 1e-12f);
  if (t < 256) outp[(size_t)g * 256 + t] = o * scale;
}

// ---------------- launch ----------------

extern "C" void kernel_launch(void* const* d_in, const int* in_sizes, int n_in,
                              void* d_out, int out_size, void* d_ws, size_t ws_size,
                              hipStream_t stream) {
  const float* x         = (const float*)d_in[0];
  const float* edge_attr = (const float*)d_in[1];
  const float* We0  = (const float*)d_in[2];
  const float* be0  = (const float*)d_in[3];
  const float* Wn0  = (const float*)d_in[4];
  const float* bno0 = (const float*)d_in[5];
  const float* g0   = (const float*)d_in[6];
  const float* bt0  = (const float*)d_in[7];
  const float* m0   = (const float*)d_in[8];
  const float* v0   = (const float*)d_in[9];
  const float* Wr0  = (const float*)d_in[10];
  const float* br0  = (const float*)d_in[11];
  const float* We_s = (const float*)d_in[12];
  const float* be_s = (const float*)d_in[13];
  const float* Wn_s = (const float*)d_in[14];
  const float* bno_s= (const float*)d_in[15];
  const float* g_s  = (const float*)d_in[16];
  const float* bt_s = (const float*)d_in[17];
  const float* m_s  = (const float*)d_in[18];
  const float* v_s  = (const float*)d_in[19];
  const float* W1   = (const float*)d_in[20];
  const float* b1   = (const float*)d_in[21];
  const float* g1   = (const float*)d_in[22];
  const float* bt1  = (const float*)d_in[23];
  const float* m1   = (const float*)d_in[24];
  const float* v1   = (const float*)d_in[25];
  const float* W2   = (const float*)d_in[26];
  const float* b2   = (const float*)d_in[27];
  const int* edge_index = (const int*)d_in[28];
  const int* batch      = (const int*)d_in[29];
  float* outp = (float*)d_out;

  char* ws = (char*)d_ws;
  size_t off = 0;
  auto alloc = [&](size_t bytes) -> void* {
    void* p = ws + off;
    off = (off + bytes + 255) & ~(size_t)255;
    return p;
  };
  unsigned short* hAHi = (unsigned short*)alloc((size_t)NPAD * HD * 2);
  unsigned short* hALo = (unsigned short*)alloc((size_t)NPAD * HD * 2);
  unsigned short* hBHi = (unsigned short*)alloc((size_t)NPAD * HD * 2);
  unsigned short* hBLo = (unsigned short*)alloc((size_t)NPAD * HD * 2);
  float* Se    = (float*)alloc((size_t)NPAD * 2 * 4);
  int*   deg   = (int*)alloc((size_t)NPAD * 4);
  int*   rowptr= (int*)alloc((size_t)(NN + 1) * 4);
  int*   rank  = (int*)alloc((size_t)NE * 4);
  int*   csr   = (int*)alloc((size_t)NE * 4);
  float* eap   = (float*)alloc((size_t)NE * 2 * 4);
  int*   bsum  = (int*)alloc(64 * 4);
  float* cw    = (float*)alloc((size_t)8 * CWS * 4);
  unsigned short* wmf = (unsigned short*)alloc((size_t)7 * WMF_L * 2);
  (void)ws_size; (void)n_in; (void)in_sizes; (void)out_size;

  hipMemsetAsync(deg, 0, (size_t)NPAD * 4, stream);

  k_deg_combine<<<DEG_BLOCKS + CMB_BLOCKS, 256, 0, stream>>>(
      edge_index, deg, rank, We0, be0, Wn0, We_s, be_s, Wn_s, cw, wmf);
  k_scanA<<<49, 1024, 0, stream>>>(deg, rowptr, bsum);
  k_scanC<<<49, 1024, 0, stream>>>(rowptr, bsum);
  k_scatter<<<(NE + 255) / 256, 256, 0, stream>>>(edge_index, edge_attr, rowptr, rank, csr, eap);
  k_node0<<<(NN + 7) / 8, 256, 0, stream>>>(rowptr, csr, eap, x, deg, cw,
                                            bno0, g0, bt0, m0, v0, Wr0, br0,
                                            Se, hAHi, hALo);

  unsigned short* curHi = hAHi; unsigned short* curLo = hALo;
  unsigned short* othHi = hBHi; unsigned short* othLo = hBLo;
  for (int l = 1; l <= 7; ++l) {
    int li = l - 1;
    k_layer<<<NPAD / TR, 256, 0, stream>>>(curHi, curLo, rowptr, csr,
        cw + (size_t)l * CWS, wmf + (size_t)li * WMF_L,
        bno_s + li * HD, g_s + li * HD, bt_s + li * HD, m_s + li * HD, v_s + li * HD,
        Se, deg, othHi, (l == 7) ? nullptr : othLo);
    unsigned short* t;
    t = curHi; curHi = othHi; othHi = t;
    t = curLo; curLo = othLo; othLo = t;
  }

  k_poolhead<<<NG, 512, 0, stream>>>(curHi, batch, W1, b1, g1, bt1, m1, v1, W2, b2, outp);
}

// Round 13
// 478.214 us; speedup vs baseline: 1.1551x; 1.1551x over previous
//
#include <hip/hip_runtime.h>

constexpr int NN   = 50000;   // nodes
constexpr int NPAD = 50016;   // padded (divisible by 16) for layer tiles
constexpr int NE   = 600000;  // edges
constexpr int NG   = 512;     // graphs
constexpr int HD   = 128;     // hidden
constexpr float BN_EPS = 1e-5f;
constexpr int CWS  = HD*HD + 2*HD + HD;  // per-layer f32 slot: Wc[128x128], wce[2x128], bc[128]
constexpr int WMF_L = 2*4*4*128*8;       // per-layer split-weight table (ushorts): [hi|lo][ks][ksub][col][8]
constexpr int TR   = 16;                 // rows per k_layer tile
constexpr int DEG_BLOCKS = (NE + 255) / 256;   // 2344
constexpr int CMB_UNITS  = 8 * 131;            // (layer, row) units for combine
constexpr int CMB_BLOCKS = CMB_UNITS / 2;      // 524 blocks x 2 units (128 thr each)

typedef __attribute__((ext_vector_type(8))) short bf16x8;
typedef __attribute__((ext_vector_type(4))) float f32x4;

__device__ inline unsigned short bf16rne(float v) {
  unsigned u = __float_as_uint(v);
  return (unsigned short)((u + 0x7FFFu + ((u >> 16) & 1u)) >> 16);
}
// split f32 into hi+lo bf16 (v ~= hi + lo, error ~2^-18 relative)
__device__ inline void bfsplit(float v, unsigned short& h, unsigned short& l) {
  unsigned short hb = bf16rne(v);
  float hf = __uint_as_float((unsigned)hb << 16);
  l = bf16rne(v - hf);
  h = hb;
}
__device__ inline float blo(unsigned u) { return __uint_as_float(u << 16); }
__device__ inline float bhi(unsigned u) { return __uint_as_float(u & 0xFFFF0000u); }

// ---------------- fused deg histogram + combined-weight build (independent work) ----------------

__global__ __launch_bounds__(256) void k_deg_combine(
    const int* __restrict__ ei, int* __restrict__ deg, int* __restrict__ rank,
    const float* __restrict__ We0, const float* __restrict__ be0, const float* __restrict__ Wn0,
    const float* __restrict__ We_s, const float* __restrict__ be_s, const float* __restrict__ Wn_s,
    float* __restrict__ cw, unsigned short* __restrict__ wmf) {
  int b = blockIdx.x;
  if (b < DEG_BLOCKS) {
    int e = b * 256 + threadIdx.x;
    if (e < NE) rank[e] = atomicAdd(&deg[ei[NE + e]], 1);
    return;
  }
  int u = (b - DEG_BLOCKS) * 2 + (threadIdx.x >> 7);
  int l = u / 131, r = u % 131, j = threadIdx.x & 127;
  float* slot = cw + (size_t)l * CWS;
  const float* Wn;
  const float* Arow;
  float* dst;
  if (l == 0) {
    Wn = Wn0;
    if (r < 4)       { Arow = We0 + r * HD; dst = slot + r * HD; }
    else if (r < 6)  { Arow = We0 + r * HD; dst = slot + HD * HD + (r - 4) * HD; }
    else if (r == 6) { Arow = be0;          dst = slot + HD * HD + 2 * HD; }
    else return;
  } else {
    int li = l - 1;
    Wn = Wn_s + (size_t)li * HD * HD;
    const float* We = We_s + (size_t)li * 130 * HD;
    if (r < 128)      { Arow = We + r * HD;  dst = slot + r * HD; }
    else if (r < 130) { Arow = We + r * HD;  dst = slot + HD * HD + (r - 128) * HD; }
    else              { Arow = be_s + li * HD; dst = slot + HD * HD + 2 * HD; }
  }
  float acc = 0.f;
  for (int t = 0; t < HD; t++) acc = fmaf(Arow[t], Wn[t * HD + j], acc);
  dst[j] = acc;
  if (l >= 1 && r < 128) {
    unsigned short hb, lb;
    bfsplit(acc, hb, lb);
    size_t wbase = (size_t)(l - 1) * WMF_L;
    int kb = r >> 5, ks2 = (r >> 3) & 3, jj = r & 7;  // k = r
    size_t o = (size_t)((kb * 4 + ks2) * 128 + j) * 8 + jj;
    wmf[wbase + o] = hb;
    wmf[wbase + WMF_L / 2 + o] = lb;
  }
}

// ---------------- scans ----------------

__global__ __launch_bounds__(1024) void k_scanA(const int* __restrict__ deg,
                                                int* __restrict__ rowptr, int* __restrict__ bsum) {
  __shared__ int sm[1024];
  int t = threadIdx.x, b = blockIdx.x;
  int i = b * 1024 + t;
  int v = (i < NN) ? deg[i] : 0;
  sm[t] = v;
  __syncthreads();
  for (int off = 1; off < 1024; off <<= 1) {
    int add = (t >= off) ? sm[t - off] : 0;
    __syncthreads();
    sm[t] += add;
    __syncthreads();
  }
  int incl = sm[t];
  if (i < NN) rowptr[i] = incl - v;   // exclusive within chunk
  if (t == 1023) bsum[b] = incl;
}

// scanB folded in: each block serially prefixes the 49 chunk sums itself
__global__ __launch_bounds__(1024) void k_scanC(int* rowptr, const int* __restrict__ bsum) {
  __shared__ int base;
  int b = blockIdx.x;
  if (threadIdx.x == 0) {
    int acc = 0;
    for (int j = 0; j < b; j++) acc += bsum[j];
    base = acc;
    if (b == 0) rowptr[NN] = NE;
  }
  __syncthreads();
  int i = b * 1024 + threadIdx.x;
  if (i < NN) rowptr[i] += base;
}

// atomic-free scatter of src index + permuted edge_attr into CSR order
__global__ __launch_bounds__(256) void k_scatter(
    const int* __restrict__ ei, const float* __restrict__ ea, const int* __restrict__ rowptr,
    const int* __restrict__ rank, int* __restrict__ csr, float* __restrict__ eap) {
  int e = blockIdx.x * 256 + threadIdx.x;
  if (e >= NE) return;
  int s = ei[e], d = ei[NE + e];
  int pos = rowptr[d] + rank[e];
  csr[pos] = s;
  *(float2*)(eap + 2 * (size_t)pos) = *(const float2*)(ea + 2 * (size_t)e);
}

// ---------------- fused node_pre + layer0: per-node sums -> K=4 conv -> hi/lo planes ----------------
// 32-lane group per node; xor-reduce leaves sums in ALL lanes; each lane computes 4 channels.
__global__ __launch_bounds__(256) void k_node0(
    const int* __restrict__ rowptr, const int* __restrict__ csr, const float* __restrict__ eap,
    const float* __restrict__ x, const int* __restrict__ deg, const float* __restrict__ cw0,
    const float* __restrict__ bno0, const float* __restrict__ g0, const float* __restrict__ bt0,
    const float* __restrict__ m0, const float* __restrict__ v0,
    const float* __restrict__ Wr0, const float* __restrict__ br0,
    float* __restrict__ Se, unsigned short* __restrict__ outHi, unsigned short* __restrict__ outLo) {
  int g32 = threadIdx.x >> 5;
  int i = blockIdx.x * 8 + g32;
  if (i >= NN) return;
  int l = threadIdx.x & 31;
  int e0 = rowptr[i], e1 = rowptr[i + 1];
  float sx0 = 0.f, sx1 = 0.f, sx2 = 0.f, sx3 = 0.f, se0 = 0.f, se1 = 0.f;
  for (int e = e0 + l; e < e1; e += 32) {
    int s = csr[e];
    float4 xv = *(const float4*)(x + 4 * (size_t)s);
    sx0 += xv.x; sx1 += xv.y; sx2 += xv.z; sx3 += xv.w;
    float2 ev = *(const float2*)(eap + 2 * (size_t)e);
    se0 += ev.x; se1 += ev.y;
  }
#pragma unroll
  for (int m = 1; m <= 16; m <<= 1) {
    sx0 += __shfl_xor(sx0, m); sx1 += __shfl_xor(sx1, m);
    sx2 += __shfl_xor(sx2, m); sx3 += __shfl_xor(sx3, m);
    se0 += __shfl_xor(se0, m); se1 += __shfl_xor(se1, m);
  }
  if (l == 0) *(float2*)(Se + 2 * (size_t)i) = make_float2(se0, se1);
  // layer0 compute for channels c = l*4 .. l*4+3
  float dg = (float)deg[i];
  float dgi = 1.0f / fmaxf(dg, 1.0f);
  float4 xr = *(const float4*)(x + 4 * (size_t)i);
  const float* Wc0  = cw0;                 // [4][128]
  const float* wce0 = cw0 + HD * HD;       // [2][128]
  const float* bc0  = cw0 + HD * HD + 2 * HD;
  ushort4 hs, ls;
  unsigned short* hp = (unsigned short*)&hs;
  unsigned short* lp = (unsigned short*)&ls;
#pragma unroll
  for (int k2 = 0; k2 < 4; k2++) {
    int c = l * 4 + k2;
    float y = sx0 * Wc0[c] + sx1 * Wc0[HD + c] + sx2 * Wc0[2 * HD + c] + sx3 * Wc0[3 * HD + c];
    y += se0 * wce0[c] + se1 * wce0[HD + c] + dg * bc0[c];
    y = y * dgi + bno0[c];
    float sc = g0[c] * rsqrtf(v0[c] + BN_EPS);
    y = (y - m0[c]) * sc + bt0[c];
    float r = br0[c] + xr.x * Wr0[c] + xr.y * Wr0[HD + c] + xr.z * Wr0[2 * HD + c] + xr.w * Wr0[3 * HD + c];
    float o = fmaxf(y + r, 0.f);
    bfsplit(o, hp[k2], lp[k2]);
  }
  *(ushort4*)(outHi + (size_t)i * HD + l * 4) = hs;
  *(ushort4*)(outLo + (size_t)i * HD + l * 4) = ls;
}

// ---------------- fused layer: half-per-row gather + MFMA GEMM + epilogue ----------------
// R10 form (best measured, 485 us total): each 32-lane half owns one row (uint2/lane
// = one load instruction covers 2 edges / 512 B / 8 lines), 4-deep unroll, register
// accumulators, no shfl, no atomics (R8: LDS f32 atomics serialized 10x).
// WLO is a COMPILE-TIME flag: R12's runtime `if (outLo)` cost ~10us/layer
// (+13.5 MB WRITE) -- last-layer Lo-skip must be a separate instantiation.

template<bool WLO>
__global__ __launch_bounds__(256, 8) void k_layer(
    const unsigned short* __restrict__ hHi, const unsigned short* __restrict__ hLo,
    const int* __restrict__ rowptr, const int* __restrict__ csr,
    const float* __restrict__ cwl, const unsigned short* __restrict__ wmf,
    const float* __restrict__ bno, const float* __restrict__ gam, const float* __restrict__ bet,
    const float* __restrict__ mu, const float* __restrict__ var,
    const float* __restrict__ Se, const int* __restrict__ deg,
    unsigned short* __restrict__ outHi, unsigned short* __restrict__ outLo) {
  __shared__ unsigned short St_hi[TR * 136];  // 136-pad, 16B-aligned rows
  __shared__ unsigned short St_lo[TR * 136];
  int tid = threadIdx.x;
  int wid = tid >> 6, lane = tid & 63;
  int half = lane >> 5, l5 = lane & 31;
  int rowbase = blockIdx.x * TR;
  const uint2* hb2 = (const uint2*)hHi;   // bf16 row = 32 uint2 = 256 B

  // ---- phase A: each half aggregates 2 rows (its parity of the wave's 4) ----
#pragma unroll
  for (int rp = 0; rp < 2; rp++) {
    int lr = wid * 4 + rp * 2 + half;
    int i = rowbase + lr;
    int e = 0, e1 = 0;
    if (i < NN) { e = rowptr[i]; e1 = rowptr[i + 1]; }
    float a0 = 0.f, a1 = 0.f, a2 = 0.f, a3 = 0.f;
    for (; e + 3 < e1; e += 4) {          // 4 loads in flight per half
      int s0 = csr[e], s1 = csr[e + 1], s2 = csr[e + 2], s3 = csr[e + 3];
      uint2 v0 = hb2[(size_t)s0 * 32 + l5];
      uint2 v1 = hb2[(size_t)s1 * 32 + l5];
      uint2 v2 = hb2[(size_t)s2 * 32 + l5];
      uint2 v3 = hb2[(size_t)s3 * 32 + l5];
      a0 += blo(v0.x) + blo(v1.x) + blo(v2.x) + blo(v3.x);
      a1 += bhi(v0.x) + bhi(v1.x) + bhi(v2.x) + bhi(v3.x);
      a2 += blo(v0.y) + blo(v1.y) + blo(v2.y) + blo(v3.y);
      a3 += bhi(v0.y) + bhi(v1.y) + bhi(v2.y) + bhi(v3.y);
    }
    if (e + 1 < e1) {
      int s0 = csr[e], s1 = csr[e + 1];
      uint2 v0 = hb2[(size_t)s0 * 32 + l5];
      uint2 v1 = hb2[(size_t)s1 * 32 + l5];
      a0 += blo(v0.x) + blo(v1.x); a1 += bhi(v0.x) + bhi(v1.x);
      a2 += blo(v0.y) + blo(v1.y); a3 += bhi(v0.y) + bhi(v1.y);
      e += 2;
    }
    if (e < e1) {
      uint2 v = hb2[(size_t)csr[e] * 32 + l5];
      a0 += blo(v.x); a1 += bhi(v.x); a2 += blo(v.y); a3 += bhi(v.y);
    }
    unsigned short h0, l0, h1, l1, h2, l2, h3, l3;
    bfsplit(a0, h0, l0); bfsplit(a1, h1, l1); bfsplit(a2, h2, l2); bfsplit(a3, h3, l3);
    *(ushort4*)&St_hi[lr * 136 + l5 * 4] = make_ushort4(h0, h1, h2, h3);
    *(ushort4*)&St_lo[lr * 136 + l5 * 4] = make_ushort4(l0, l1, l2, l3);
  }
  __syncthreads();

  // ---- phase B: MFMA GEMM. Wave grid 1(M)x4(N): 16 rows x 32 cols per wave ----
  int nlane = lane & 15, ksub = lane >> 4;
  const unsigned short* wh = wmf;                 // hi table [ks][ksub][col][8]
  const unsigned short* wl = wmf + WMF_L / 2;     // lo table
  f32x4 acc[2];
#pragma unroll
  for (int nt = 0; nt < 2; nt++) acc[nt] = (f32x4){0.f, 0.f, 0.f, 0.f};
#pragma unroll
  for (int ks = 0; ks < 4; ks++) {
    bf16x8 ah = *(const bf16x8*)&St_hi[nlane * 136 + ks * 32 + ksub * 8];
    bf16x8 al = *(const bf16x8*)&St_lo[nlane * 136 + ks * 32 + ksub * 8];
#pragma unroll
    for (int nt = 0; nt < 2; nt++) {
      int col = wid * 32 + nt * 16 + nlane;
      bf16x8 bh = *(const bf16x8*)&wh[(size_t)((ks * 4 + ksub) * 128 + col) * 8];
      bf16x8 bl = *(const bf16x8*)&wl[(size_t)((ks * 4 + ksub) * 128 + col) * 8];
      acc[nt] = __builtin_amdgcn_mfma_f32_16x16x32_bf16(ah, bh, acc[nt], 0, 0, 0);
      acc[nt] = __builtin_amdgcn_mfma_f32_16x16x32_bf16(al, bh, acc[nt], 0, 0, 0);
      acc[nt] = __builtin_amdgcn_mfma_f32_16x16x32_bf16(ah, bl, acc[nt], 0, 0, 0);
    }
  }

  // ---- epilogue: C/D frag lane l reg i -> row=(l>>4)*4+i, col=(l&15)+16*nt ----
  const float* wce = cwl + HD * HD;
  const float* bcp = cwl + HD * HD + 2 * HD;
  int rb = ksub * 4;
  float dgv[4], dgiv[4];
  float2 sevv[4];
#pragma unroll
  for (int i2 = 0; i2 < 4; i2++) {
    size_t row = (size_t)rowbase + rb + i2;
    float dg = (float)deg[row];
    dgv[i2] = dg;
    dgiv[i2] = 1.0f / fmaxf(dg, 1.0f);
    sevv[i2] = *(const float2*)(Se + row * 2);
  }
#pragma unroll
  for (int nt = 0; nt < 2; nt++) {
    int col = wid * 32 + nt * 16 + nlane;
    float w0 = wce[col], w1 = wce[HD + col], bcv = bcp[col], bnov = bno[col];
    float sc = gam[col] * rsqrtf(var[col] + BN_EPS);
    float sh = bet[col] - mu[col] * sc;
#pragma unroll
    for (int i2 = 0; i2 < 4; i2++) {
      size_t row = (size_t)rowbase + rb + i2;
      size_t idx = row * HD + col;
      float res = __uint_as_float((unsigned)hHi[idx] << 16)
                + __uint_as_float((unsigned)hLo[idx] << 16);
      float y = (acc[nt][i2] + sevv[i2].x * w0 + sevv[i2].y * w1 + dgv[i2] * bcv) * dgiv[i2] + bnov;
      y = fmaxf(y * sc + sh + res, 0.f);
      unsigned short yh, yl;
      bfsplit(y, yh, yl);
      outHi[idx] = yh;
      if constexpr (WLO) outLo[idx] = yl;   // compile-time: last layer skips Lo plane
    }
  }
}

// ---------------- fused pooling + head: pooled vectors stay in LDS ----------------

__global__ __launch_bounds__(512) void k_poolhead(
    const unsigned short* __restrict__ hb, const int* __restrict__ batch,
    const float* __restrict__ W1, const float* __restrict__ b1,
    const float* __restrict__ g1, const float* __restrict__ bt1,
    const float* __restrict__ m1, const float* __restrict__ v1,
    const float* __restrict__ W2, const float* __restrict__ b2,
    float* __restrict__ outp) {
  __shared__ float ssum[512], smax[512];
  __shared__ float pmean[128], pmax[128];
  __shared__ float s1[128];
  __shared__ float red[512];
  int g = blockIdx.x, t = threadIdx.x;
  int d = t & 127, sub = t >> 7;   // 4-way row split
  int lo = 0, hi = NN;
  while (lo < hi) { int mid = (lo + hi) >> 1; if (batch[mid] < g) lo = mid + 1; else hi = mid; }
  int start = lo;
  lo = start; hi = NN;
  while (lo < hi) { int mid = (lo + hi) >> 1; if (batch[mid] < g + 1) lo = mid + 1; else hi = mid; }
  int end = lo;
  float sum = 0.f, mx = -3.4e38f;
  for (int i = start + sub; i < end; i += 4) {
    float val = __uint_as_float((unsigned)hb[(size_t)i * HD + d] << 16);
    sum += val;
    mx = fmaxf(mx, val);
  }
  ssum[t] = sum; smax[t] = mx;
  __syncthreads();
  if (sub == 0) {
    sum = ssum[t] + ssum[t + 128] + ssum[t + 256] + ssum[t + 384];
    mx = fmaxf(fmaxf(smax[t], smax[t + 128]), fmaxf(smax[t + 256], smax[t + 384]));
    int cnt = end - start;
    pmean[d] = sum / fmaxf((float)cnt, 1.f);
    pmax[d] = (cnt > 0) ? mx : 0.f;
  }
  __syncthreads();
  if (t < 128) {
    float y = b1[t];
    for (int k = 0; k < 128; k++) y = fmaf(pmean[k], W1[k * HD + t], y);
    for (int k = 0; k < 128; k++) y = fmaf(pmax[k], W1[(128 + k) * HD + t], y);
    float sc = g1[t] * rsqrtf(v1[t] + BN_EPS);
    y = (y - m1[t]) * sc + bt1[t];
    s1[t] = fmaxf(y, 0.f);
  }
  __syncthreads();
  float o = 0.f;
  if (t < 256) {
    o = b2[t];
    for (int k = 0; k < 128; k++) o = fmaf(s1[k], W2[k * 256 + t], o);
  }
  red[t] = o * o;
  __syncthreads();
  for (int off = 256; off > 0; off >>= 1) {
    if (t < off) red[t] += red[t + off];
    __syncthreads();
  }
  float scale = 1.0f / fmaxf(sqrtf(red[0]), 1e-12f);
  if (t < 256) outp[(size_t)g * 256 + t] = o * scale;
}

// ---------------- launch ----------------

extern "C" void kernel_launch(void* const* d_in, const int* in_sizes, int n_in,
                              void* d_out, int out_size, void* d_ws, size_t ws_size,
                              hipStream_t stream) {
  const float* x         = (const float*)d_in[0];
  const float* edge_attr = (const float*)d_in[1];
  const float* We0  = (const float*)d_in[2];
  const float* be0  = (const float*)d_in[3];
  const float* Wn0  = (const float*)d_in[4];
  const float* bno0 = (const float*)d_in[5];
  const float* g0   = (const float*)d_in[6];
  const float* bt0  = (const float*)d_in[7];
  const float* m0   = (const float*)d_in[8];
  const float* v0   = (const float*)d_in[9];
  const float* Wr0  = (const float*)d_in[10];
  const float* br0  = (const float*)d_in[11];
  const float* We_s = (const float*)d_in[12];
  const float* be_s = (const float*)d_in[13];
  const float* Wn_s = (const float*)d_in[14];
  const float* bno_s= (const float*)d_in[15];
  const float* g_s  = (const float*)d_in[16];
  const float* bt_s = (const float*)d_in[17];
  const float* m_s  = (const float*)d_in[18];
  const float* v_s  = (const float*)d_in[19];
  const float* W1   = (const float*)d_in[20];
  const float* b1   = (const float*)d_in[21];
  const float* g1   = (const float*)d_in[22];
  const float* bt1  = (const float*)d_in[23];
  const float* m1   = (const float*)d_in[24];
  const float* v1   = (const float*)d_in[25];
  const float* W2   = (const float*)d_in[26];
  const float* b2   = (const float*)d_in[27];
  const int* edge_index = (const int*)d_in[28];
  const int* batch      = (const int*)d_in[29];
  float* outp = (float*)d_out;

  char* ws = (char*)d_ws;
  size_t off = 0;
  auto alloc = [&](size_t bytes) -> void* {
    void* p = ws + off;
    off = (off + bytes + 255) & ~(size_t)255;
    return p;
  };
  unsigned short* hAHi = (unsigned short*)alloc((size_t)NPAD * HD * 2);
  unsigned short* hALo = (unsigned short*)alloc((size_t)NPAD * HD * 2);
  unsigned short* hBHi = (unsigned short*)alloc((size_t)NPAD * HD * 2);
  unsigned short* hBLo = (unsigned short*)alloc((size_t)NPAD * HD * 2);
  float* Se    = (float*)alloc((size_t)NPAD * 2 * 4);
  int*   deg   = (int*)alloc((size_t)NPAD * 4);
  int*   rowptr= (int*)alloc((size_t)(NN + 1) * 4);
  int*   rank  = (int*)alloc((size_t)NE * 4);
  int*   csr   = (int*)alloc((size_t)NE * 4);
  float* eap   = (float*)alloc((size_t)NE * 2 * 4);
  int*   bsum  = (int*)alloc(64 * 4);
  float* cw    = (float*)alloc((size_t)8 * CWS * 4);
  unsigned short* wmf = (unsigned short*)alloc((size_t)7 * WMF_L * 2);
  (void)ws_size; (void)n_in; (void)in_sizes; (void)out_size;

  hipMemsetAsync(deg, 0, (size_t)NPAD * 4, stream);

  k_deg_combine<<<DEG_BLOCKS + CMB_BLOCKS, 256, 0, stream>>>(
      edge_index, deg, rank, We0, be0, Wn0, We_s, be_s, Wn_s, cw, wmf);
  k_scanA<<<49, 1024, 0, stream>>>(deg, rowptr, bsum);
  k_scanC<<<49, 1024, 0, stream>>>(rowptr, bsum);
  k_scatter<<<(NE + 255) / 256, 256, 0, stream>>>(edge_index, edge_attr, rowptr, rank, csr, eap);
  k_node0<<<(NN + 7) / 8, 256, 0, stream>>>(rowptr, csr, eap, x, deg, cw,
                                            bno0, g0, bt0, m0, v0, Wr0, br0,
                                            Se, hAHi, hALo);

  unsigned short* curHi = hAHi; unsigned short* curLo = hALo;
  unsigned short* othHi = hBHi; unsigned short* othLo = hBLo;
  for (int l = 1; l <= 7; ++l) {
    int li = l - 1;
    if (l < 7) {
      k_layer<true><<<NPAD / TR, 256, 0, stream>>>(curHi, curLo, rowptr, csr,
          cw + (size_t)l * CWS, wmf + (size_t)li * WMF_L,
          bno_s + li * HD, g_s + li * HD, bt_s + li * HD, m_s + li * HD, v_s + li * HD,
          Se, deg, othHi, othLo);
    } else {
      k_layer<false><<<NPAD / TR, 256, 0, stream>>>(curHi, curLo, rowptr, csr,
          cw + (size_t)l * CWS, wmf + (size_t)li * WMF_L,
          bno_s + li * HD, g_s + li * HD, bt_s + li * HD, m_s + li * HD, v_s + li * HD,
          Se, deg, othHi, othLo);
    }
    unsigned short* t;
    t = curHi; curHi = othHi; othHi = t;
    t = curLo; curLo = othLo; othLo = t;
  }

  k_poolhead<<<NG, 512, 0, stream>>>(curHi, batch, W1, b1, g1, bt1, m1, v1, W2, b2, outp);
}